// Round 1
// baseline (243967.432 us; speedup 1.0000x reference)
//
#include <hip/hip_runtime.h>
#include <math.h>

// Problem constants (avoid single-letter macros: they break HIP headers)
constexpr int BSZ  = 256;   // batch
constexpr int TLEN = 128;   // sequence length
constexpr int LLEN = 64;    // encoder length
constexpr int DH   = 512;   // hidden
constexpr int EMBD = 128;   // action embed
constexpr int ACTN = 129;   // action size + 1
constexpr int HATT = 20;    // attention MLP hidden

// ---------------------------------------------------------------------------
// Generic strided transpose: dst[c*dld + r] = src[r*sld + c]
// ---------------------------------------------------------------------------
__global__ void k_tr(float* __restrict__ dst, const float* __restrict__ src,
                     int R, int C, int sld, int dld)
{
    int idx = blockIdx.x * 256 + threadIdx.x;
    if (idx >= R * C) return;
    int c = idx / R, r = idx - c * R;
    dst[c * dld + r] = src[r * sld + c];
}

// ---------------------------------------------------------------------------
// Fold attn_combine into LSTM1: WT1[k][n] = sum_m Wih1[n][m] * Wc[m][k]
// k<640, n<2048, m<512.  Tiled 64x64, 256 threads, 4x4 per thread.
// ---------------------------------------------------------------------------
__launch_bounds__(256)
__global__ void k_fold(const float* __restrict__ Wih1, const float* __restrict__ Wc,
                       float* __restrict__ WT1)
{
    __shared__ float at[64][33];  // Wih1 tile [n][m]
    __shared__ float bt[32][65];  // Wc tile   [m][k]
    int tid = threadIdx.x;
    int tx = tid & 15, ty = tid >> 4;        // tx: k dir, ty: n dir
    int n0 = blockIdx.x * 64, k0 = blockIdx.y * 64;
    float acc[4][4] = {};
    for (int m0 = 0; m0 < 512; m0 += 32) {
        for (int i = 0; i < 8; ++i) {
            int idx = tid + 256 * i;          // 2048 elems
            int nl = idx >> 5, ml = idx & 31;
            at[nl][ml] = Wih1[(n0 + nl) * 512 + m0 + ml];
        }
        for (int i = 0; i < 8; ++i) {
            int idx = tid + 256 * i;
            int ml = idx >> 6, kl = idx & 63;
            bt[ml][kl] = Wc[(m0 + ml) * 640 + k0 + kl];
        }
        __syncthreads();
        for (int m = 0; m < 32; ++m) {
            #pragma unroll
            for (int i = 0; i < 4; ++i) {
                float av = at[ty * 4 + i][m];
                #pragma unroll
                for (int j = 0; j < 4; ++j)
                    acc[i][j] += av * bt[m][tx * 4 + j];
            }
        }
        __syncthreads();
    }
    for (int i = 0; i < 4; ++i)
        for (int j = 0; j < 4; ++j)
            WT1[(size_t)(k0 + tx * 4 + j) * 2048 + (n0 + ty * 4 + i)] = acc[i][j];
}

// ---------------------------------------------------------------------------
// Combined biases: b1f = bih1 + bhh1 + Wih1 @ bc ; b2/b3 simple sums.
// ---------------------------------------------------------------------------
__global__ void k_bias(const float* __restrict__ Wih1, const float* __restrict__ bc,
                       const float* bih1, const float* bhh1,
                       const float* bih2, const float* bhh2,
                       const float* bih3, const float* bhh3,
                       float* b1f, float* b2, float* b3)
{
    int n = blockIdx.x * 256 + threadIdx.x;   // 2048
    float s = bih1[n] + bhh1[n];
    for (int m = 0; m < 512; ++m) s += Wih1[n * 512 + m] * bc[m];
    b1f[n] = s;
    b2[n] = bih2[n] + bhh2[n];
    b3[n] = bih3[n] + bhh3[n];
}

// ---------------------------------------------------------------------------
// Precompute encoder part of attention MLP:
// ENCP[b][l][h] = sum_e enc[b][l][e] * Wa1[h][e] + ba1[h]    (e < 512)
// one block per b, 64 rows each.
// ---------------------------------------------------------------------------
__launch_bounds__(256)
__global__ void k_encp(const float* __restrict__ enc, const float* __restrict__ Wa1,
                       const float* __restrict__ ba1, float* __restrict__ ENCP)
{
    __shared__ float wa[HATT * 513];
    __shared__ float er[8][513];
    int b = blockIdx.x, tid = threadIdx.x;
    for (int idx = tid; idx < HATT * 512; idx += 256) {
        int h = idx >> 9, e = idx & 511;
        wa[h * 513 + e] = Wa1[h * 1024 + e];
    }
    __syncthreads();
    for (int c = 0; c < 8; ++c) {
        for (int i = 0; i < 16; ++i) {
            int idx = tid + 256 * i;          // 4096
            int rr = idx >> 9, e = idx & 511;
            er[rr][e] = enc[((size_t)b * LLEN + c * 8 + rr) * 512 + e];
        }
        __syncthreads();
        if (tid < 8 * HATT) {
            int rr = tid & 7, h = tid >> 3;
            float s = 0.f;
            for (int e = 0; e < 512; ++e) s += er[rr][e] * wa[h * 513 + e];
            ENCP[((size_t)b * LLEN + c * 8 + rr) * HATT + h] = s + ba1[h];
        }
        __syncthreads();
    }
}

// ---------------------------------------------------------------------------
// State init: h0=h1=h2=enc_h, c0=c1=c2=enc_c, ctx=0
// ---------------------------------------------------------------------------
__global__ void k_init(const float* __restrict__ eh, const float* __restrict__ ec,
                       float* h0, float* c0, float* h1, float* c1,
                       float* h2, float* c2, float* ctx)
{
    int i = blockIdx.x * 256 + threadIdx.x;   // 131072
    float h = eh[i], c = ec[i];
    h0[i] = h; h1[i] = h; h2[i] = h;
    c0[i] = c; c1[i] = c; c2[i] = c;
    ctx[i] = 0.f;
}

// ---------------------------------------------------------------------------
// LSTM gates + cell update.
// gates[b][n] = sum_k A[b][k] * WT[k][n] + bias[n]
// stage1 (s1=1): A = [embed(t-1) (128) | ctx (512) | h0 (512)], K=1152, WT1 folded
// stage2/3:      A = [x (512) | h (512)], K=1024
// grid (8, 32): 32 rows x 16 h-cols per block. 256 threads.
// ---------------------------------------------------------------------------
__launch_bounds__(256)
__global__ void k_gates(const float* __restrict__ WT, const float* __restrict__ bias,
                        int s1, int t,
                        const int* __restrict__ act, const float* __restrict__ embW,
                        const float* __restrict__ xa,   // s1: ctx; else x
                        const float* __restrict__ hin,
                        const float* __restrict__ cin,
                        float* __restrict__ hout, float* __restrict__ cout)
{
    __shared__ float As[32][129];
    const int K = s1 ? 1152 : 1024;
    const int nch = K >> 7;
    int tid = threadIdx.x;
    int r = tid >> 3;                 // 0..31 row within tile
    int hc8 = tid & 7;                // 0..7
    int brow0 = blockIdx.x * 32;
    int j0 = blockIdx.y * 16 + hc8 * 2;   // h-col base (owns j0, j0+1)
    float acc[4][2] = {};
    for (int kc = 0; kc < nch; ++kc) {
        // cooperative load of 32x128 A-chunk (coalesced over k)
        for (int i = 0; i < 16; ++i) {
            int idx = tid + 256 * i;         // 0..4095
            int rr = idx >> 7, kk = idx & 127;
            int k = kc * 128 + kk;
            int b = brow0 + rr;
            float v;
            if (s1) {
                if (k < 128)      v = (t == 0) ? 0.f
                                      : embW[act[b * TLEN + (t - 1)] * EMBD + k];
                else if (k < 640) v = xa[b * 512 + (k - 128)];
                else              v = hin[b * 512 + (k - 640)];
            } else {
                v = (k < 512) ? xa[b * 512 + k] : hin[b * 512 + (k - 512)];
            }
            As[rr][kk] = v;
        }
        __syncthreads();
        const float* wp = WT + (size_t)(kc * 128) * 2048 + j0;
        for (int kk = 0; kk < 128; ++kk) {
            float a = As[r][kk];
            #pragma unroll
            for (int g = 0; g < 4; ++g) {
                float2 wv = *(const float2*)(wp + g * 512);
                acc[g][0] += a * wv.x;
                acc[g][1] += a * wv.y;
            }
            wp += 2048;
        }
        __syncthreads();
    }
    int b = brow0 + r;
    #pragma unroll
    for (int cc = 0; cc < 2; ++cc) {
        int j = j0 + cc;
        float gi = acc[0][cc] + bias[j];
        float gf = acc[1][cc] + bias[512 + j];
        float gg = acc[2][cc] + bias[1024 + j];
        float go = acc[3][cc] + bias[1536 + j];
        float si = 1.f / (1.f + expf(-gi));
        float sf = 1.f / (1.f + expf(-gf));
        float so = 1.f / (1.f + expf(-go));
        float cn = sf * cin[b * 512 + j] + si * tanhf(gg);
        float hn = so * tanhf(cn);
        cout[b * 512 + j] = cn;
        hout[b * 512 + j] = hn;
    }
}

// ---------------------------------------------------------------------------
// Attention: h_part = h2 @ Wa1_h^T ; score = tanh(relu(ENCP+h_part) @ Wa2 + ba2)
// softmax over L; ctx = w @ enc.   One block per batch row.
// ---------------------------------------------------------------------------
__launch_bounds__(256)
__global__ void k_attn(const float* __restrict__ h2, const float* __restrict__ enc,
                       const float* __restrict__ ENCP, const float* __restrict__ WaHT,
                       const float* __restrict__ Wa2, const float* __restrict__ ba2,
                       float* __restrict__ ctx)
{
    int b = blockIdx.x, tid = threadIdx.x;
    __shared__ float h2s[512];
    __shared__ float part[8][HATT];
    __shared__ float hp[HATT];
    __shared__ float sl[LLEN];
    h2s[tid] = h2[b * 512 + tid];
    h2s[256 + tid] = h2[b * 512 + 256 + tid];
    __syncthreads();
    if (tid < 8 * HATT) {
        int h = tid % HATT, sg = tid / HATT;
        float s = 0.f;
        for (int e = sg * 64; e < sg * 64 + 64; ++e) s += h2s[e] * WaHT[e * HATT + h];
        part[sg][h] = s;
    }
    __syncthreads();
    if (tid < HATT) {
        float s = 0.f;
        for (int sg = 0; sg < 8; ++sg) s += part[sg][tid];
        hp[tid] = s;
    }
    __syncthreads();
    if (tid < LLEN) {
        float s = ba2[0];
        const float* ep = ENCP + ((size_t)b * LLEN + tid) * HATT;
        #pragma unroll
        for (int h = 0; h < HATT; ++h)
            s += fmaxf(ep[h] + hp[h], 0.f) * Wa2[h];
        float v = tanhf(s);
        // softmax over the 64 lanes of wave 0
        float m = v;
        for (int off = 32; off; off >>= 1) m = fmaxf(m, __shfl_xor(m, off));
        float e = expf(v - m);
        float ssum = e;
        for (int off = 32; off; off >>= 1) ssum += __shfl_xor(ssum, off);
        sl[tid] = e / ssum;
    }
    __syncthreads();
    for (int e = tid; e < 512; e += 256) {
        float acc = 0.f;
        for (int l = 0; l < LLEN; ++l)
            acc += sl[l] * enc[((size_t)b * LLEN + l) * 512 + e];
        ctx[b * 512 + e] = acc;
    }
}

// ---------------------------------------------------------------------------
// Head layer 1: hidden = relu([h2|ctx] @ Wl1^T + bl1)
// grid (16, 8): 16 rows x 64 cols per block.
// ---------------------------------------------------------------------------
__launch_bounds__(256)
__global__ void k_head1(const float* __restrict__ h2, const float* __restrict__ ctx,
                        const float* __restrict__ WTl1, const float* __restrict__ bl1,
                        float* __restrict__ hidden)
{
    __shared__ float As[16][129];
    int tid = threadIdx.x;
    int r = tid >> 4;             // 16 rows
    int c4 = (tid & 15) * 4;      // col quad within 64
    int brow0 = blockIdx.x * 16;
    int n0 = blockIdx.y * 64;
    float acc[4] = {};
    for (int kc = 0; kc < 8; ++kc) {
        for (int i = 0; i < 8; ++i) {
            int idx = tid + 256 * i;        // 0..2047
            int rr = idx >> 7, kk = idx & 127;
            int k = kc * 128 + kk;
            int b = brow0 + rr;
            As[rr][kk] = (k < 512) ? h2[b * 512 + k] : ctx[b * 512 + (k - 512)];
        }
        __syncthreads();
        for (int kk = 0; kk < 128; ++kk) {
            float a = As[r][kk];
            float4 wv = *(const float4*)&WTl1[(size_t)(kc * 128 + kk) * 512 + n0 + c4];
            acc[0] += a * wv.x; acc[1] += a * wv.y;
            acc[2] += a * wv.z; acc[3] += a * wv.w;
        }
        __syncthreads();
    }
    int b = brow0 + r;
    #pragma unroll
    for (int i = 0; i < 4; ++i) {
        int n = n0 + c4 + i;
        hidden[b * 512 + n] = fmaxf(acc[i] + bl1[n], 0.f);
    }
}

// ---------------------------------------------------------------------------
// Head layer 2: logits = hidden @ Wl2^T + bl2 -> out[(b*T + t)*129 + a]
// grid 64 blocks x 4 rows.
// ---------------------------------------------------------------------------
__launch_bounds__(256)
__global__ void k_head2(const float* __restrict__ hidden, const float* __restrict__ WTl2,
                        const float* __restrict__ bl2, float* __restrict__ out, int t)
{
    __shared__ float As[4][513];
    int tid = threadIdx.x;
    int r = tid >> 6, c = tid & 63;
    int brow0 = blockIdx.x * 4;
    for (int i = 0; i < 8; ++i) {
        int idx = tid + 256 * i;           // 0..2047
        int rr = idx >> 9, kk = idx & 511;
        As[rr][kk] = hidden[(brow0 + rr) * 512 + kk];
    }
    __syncthreads();
    float a0 = 0.f, a1 = 0.f, a2 = 0.f;
    for (int k = 0; k < 512; ++k) {
        float a = As[r][k];
        const float* wrow = WTl2 + k * ACTN;
        a0 += a * wrow[c];
        a1 += a * wrow[c + 64];
        if (c == 0) a2 += a * wrow[128];
    }
    size_t row = (size_t)(brow0 + r) * TLEN + t;
    out[row * ACTN + c]      = a0 + bl2[c];
    out[row * ACTN + c + 64] = a1 + bl2[c + 64];
    if (c == 0) out[row * ACTN + 128] = a2 + bl2[128];
}

// ---------------------------------------------------------------------------
// Launch
// ---------------------------------------------------------------------------
extern "C" void kernel_launch(void* const* d_in, const int* in_sizes, int n_in,
                              void* d_out, int out_size, void* d_ws, size_t ws_size,
                              hipStream_t stream)
{
    const int*   act   = (const int*)d_in[0];
    const float* enc   = (const float*)d_in[1];
    const float* enc_h = (const float*)d_in[2];
    const float* enc_c = (const float*)d_in[3];
    const float* embW  = (const float*)d_in[4];
    const float* Wc    = (const float*)d_in[5];
    const float* bc    = (const float*)d_in[6];
    const float* Wih1  = (const float*)d_in[7];
    const float* Whh1  = (const float*)d_in[8];
    const float* bih1  = (const float*)d_in[9];
    const float* bhh1  = (const float*)d_in[10];
    const float* Wih2  = (const float*)d_in[11];
    const float* Whh2  = (const float*)d_in[12];
    const float* bih2  = (const float*)d_in[13];
    const float* bhh2  = (const float*)d_in[14];
    const float* Wih3  = (const float*)d_in[15];
    const float* Whh3  = (const float*)d_in[16];
    const float* bih3  = (const float*)d_in[17];
    const float* bhh3  = (const float*)d_in[18];
    const float* Wa1   = (const float*)d_in[19];
    const float* ba1   = (const float*)d_in[20];
    const float* Wa2   = (const float*)d_in[21];
    const float* ba2   = (const float*)d_in[22];
    const float* Wl1   = (const float*)d_in[23];
    const float* bl1   = (const float*)d_in[24];
    const float* Wl2   = (const float*)d_in[25];
    const float* bl2   = (const float*)d_in[26];
    float* out = (float*)d_out;

    // workspace carve-up
    float* w = (float*)d_ws;
    float* WT1  = w; w += (size_t)1152 * 2048;
    float* WT2  = w; w += (size_t)1024 * 2048;
    float* WT3  = w; w += (size_t)1024 * 2048;
    float* b1f  = w; w += 2048;
    float* b2   = w; w += 2048;
    float* b3   = w; w += 2048;
    float* WaHT = w; w += 512 * HATT;
    float* ENCP = w; w += (size_t)BSZ * LLEN * HATT;
    float* WTl1 = w; w += (size_t)1024 * 512;
    float* WTl2 = w; w += (size_t)512 * ACTN;
    float* st   = w;                       // 13 state buffers + hidden
    const size_t SB = (size_t)BSZ * DH;
    float* h0[2] = { st + 0 * SB, st + 1 * SB };
    float* c0[2] = { st + 2 * SB, st + 3 * SB };
    float* h1[2] = { st + 4 * SB, st + 5 * SB };
    float* c1[2] = { st + 6 * SB, st + 7 * SB };
    float* h2[2] = { st + 8 * SB, st + 9 * SB };
    float* c2[2] = { st + 10 * SB, st + 11 * SB };
    float* ctx   = st + 12 * SB;
    float* hidden= st + 13 * SB;

    auto trBlocks = [](int R, int C) { return (R * C + 255) / 256; };

    // --- prep ---
    // WT1 h-part (rows 640..1151) = Whh1^T
    k_tr<<<trBlocks(2048, 512), 256, 0, stream>>>(WT1 + (size_t)640 * 2048, Whh1, 2048, 512, 512, 2048);
    // WT2 / WT3
    k_tr<<<trBlocks(2048, 512), 256, 0, stream>>>(WT2, Wih2, 2048, 512, 512, 2048);
    k_tr<<<trBlocks(2048, 512), 256, 0, stream>>>(WT2 + (size_t)512 * 2048, Whh2, 2048, 512, 512, 2048);
    k_tr<<<trBlocks(2048, 512), 256, 0, stream>>>(WT3, Wih3, 2048, 512, 512, 2048);
    k_tr<<<trBlocks(2048, 512), 256, 0, stream>>>(WT3 + (size_t)512 * 2048, Whh3, 2048, 512, 512, 2048);
    // heads / attention weights
    k_tr<<<trBlocks(512, 1024), 256, 0, stream>>>(WTl1, Wl1, 512, 1024, 1024, 512);
    k_tr<<<trBlocks(ACTN, 512), 256, 0, stream>>>(WTl2, Wl2, ACTN, 512, 512, ACTN);
    k_tr<<<trBlocks(HATT, 512), 256, 0, stream>>>(WaHT, Wa1 + 512, HATT, 512, 1024, HATT);
    // folded W1f into WT1 rows 0..639
    k_fold<<<dim3(32, 10), 256, 0, stream>>>(Wih1, Wc, WT1);
    // biases
    k_bias<<<8, 256, 0, stream>>>(Wih1, bc, bih1, bhh1, bih2, bhh2, bih3, bhh3, b1f, b2, b3);
    // encoder part of attention MLP
    k_encp<<<BSZ, 256, 0, stream>>>(enc, Wa1, ba1, ENCP);
    // init state (parity 0)
    k_init<<<512, 256, 0, stream>>>(enc_h, enc_c, h0[0], c0[0], h1[0], c1[0], h2[0], c2[0], ctx);

    // --- recurrent loop ---
    for (int t = 0; t < TLEN; ++t) {
        int p = t & 1, q = p ^ 1;
        k_gates<<<dim3(8, 32), 256, 0, stream>>>(WT1, b1f, 1, t, act, embW,
                                                 ctx, h0[p], c0[p], h0[q], c0[q]);
        k_gates<<<dim3(8, 32), 256, 0, stream>>>(WT2, b2, 0, t, act, embW,
                                                 h0[q], h1[p], c1[p], h1[q], c1[q]);
        k_gates<<<dim3(8, 32), 256, 0, stream>>>(WT3, b3, 0, t, act, embW,
                                                 h1[q], h2[p], c2[p], h2[q], c2[q]);
        k_attn<<<BSZ, 256, 0, stream>>>(h2[q], enc, ENCP, WaHT, Wa2, ba2, ctx);
        k_head1<<<dim3(16, 8), 256, 0, stream>>>(h2[q], ctx, WTl1, bl1, hidden);
        k_head2<<<64, 256, 0, stream>>>(hidden, WTl2, bl2, out, t);
    }
}

// Round 2
// 11585.035 us; speedup vs baseline: 21.0588x; 21.0588x over previous
//
#include <hip/hip_runtime.h>
#include <math.h>

constexpr int BSZ  = 256;
constexpr int TLEN = 128;
constexpr int LLEN = 64;
constexpr int DH   = 512;
constexpr int EMBD = 128;
constexpr int ACTN = 129;
constexpr int HATT = 20;

typedef short bf16x8 __attribute__((ext_vector_type(8)));
typedef float f32x4  __attribute__((ext_vector_type(4)));

__device__ __forceinline__ short f2bf(float f) {
    unsigned u = __builtin_bit_cast(unsigned, f);
    u += 0x7fffu + ((u >> 16) & 1u);
    return (short)(u >> 16);
}
__device__ __forceinline__ float bf2f(short s) {
    unsigned u = ((unsigned)(unsigned short)s) << 16;
    return __builtin_bit_cast(float, u);
}

// ---------------------------------------------------------------------------
// Fold attn_combine into LSTM1: W1f[n][k] = sum_m Wih1[n][m] * Wc[m][k]
// n<2048, k<640, m<512. 64x64 tiles.
// ---------------------------------------------------------------------------
__launch_bounds__(256)
__global__ void k_fold(const float* __restrict__ Wih1, const float* __restrict__ Wc,
                       float* __restrict__ W1f)
{
    __shared__ float at[64][33];
    __shared__ float bt[32][65];
    int tid = threadIdx.x;
    int tx = tid & 15, ty = tid >> 4;
    int n0 = blockIdx.x * 64, k0 = blockIdx.y * 64;
    float acc[4][4] = {};
    for (int m0 = 0; m0 < 512; m0 += 32) {
        for (int i = 0; i < 8; ++i) {
            int idx = tid + 256 * i;
            int nl = idx >> 5, ml = idx & 31;
            at[nl][ml] = Wih1[(size_t)(n0 + nl) * 512 + m0 + ml];
        }
        for (int i = 0; i < 8; ++i) {
            int idx = tid + 256 * i;
            int ml = idx >> 6, kl = idx & 63;
            bt[ml][kl] = Wc[(size_t)(m0 + ml) * 640 + k0 + kl];
        }
        __syncthreads();
        for (int m = 0; m < 32; ++m) {
            #pragma unroll
            for (int i = 0; i < 4; ++i) {
                float av = at[ty * 4 + i][m];
                #pragma unroll
                for (int j = 0; j < 4; ++j)
                    acc[i][j] += av * bt[m][tx * 4 + j];
            }
        }
        __syncthreads();
    }
    for (int i = 0; i < 4; ++i)
        for (int j = 0; j < 4; ++j)
            W1f[(size_t)(n0 + ty * 4 + i) * 640 + (k0 + tx * 4 + j)] = acc[i][j];
}

// ---------------------------------------------------------------------------
// Weight packing into MFMA fragment order.
// pack element index: (((nb*4 + w)*KSTEPS + ks)*64 + lane)*8 + i
// value = W(n', k) with n' = nb*64 + w*16 + (lane&15), k = ks*32 + (lane>>4)*8 + i
// LSTM packs permute columns: n_orig = (n'&3)*512 + (n'>>2)  (gate-interleave)
// ---------------------------------------------------------------------------
__global__ void k_pack23(const float* __restrict__ Wih, const float* __restrict__ Whh,
                         short* __restrict__ pack)
{
    int idx = blockIdx.x * 256 + threadIdx.x;       // 262144
    int lane = idx & 63;
    int ks = (idx >> 6) & 31;
    int w  = (idx >> 11) & 3;
    int nb = idx >> 13;
    int np = nb * 64 + w * 16 + (lane & 15);
    int k  = ks * 32 + ((lane >> 4) << 3);
    int n  = (np & 3) * 512 + (np >> 2);
    const float* src = (k < 512) ? (Wih + (size_t)n * 512 + k)
                                 : (Whh + (size_t)n * 512 + (k - 512));
    short* dst = pack + (size_t)idx * 8;
    #pragma unroll
    for (int i = 0; i < 8; ++i) dst[i] = f2bf(src[i]);
}

__global__ void k_pack1(const float* __restrict__ W1f, const float* __restrict__ Whh1,
                        short* __restrict__ pack)
{
    int idx = blockIdx.x * 256 + threadIdx.x;       // 294912
    int lane = idx & 63;
    int tmp = idx >> 6;
    int ks = tmp % 36;
    int r2 = tmp / 36;
    int w = r2 & 3, nb = r2 >> 2;
    int np = nb * 64 + w * 16 + (lane & 15);
    int k  = ks * 32 + ((lane >> 4) << 3);
    int n  = (np & 3) * 512 + (np >> 2);
    const float* src = (k < 640) ? (W1f + (size_t)n * 640 + k)
                                 : (Whh1 + (size_t)n * 512 + (k - 640));
    short* dst = pack + (size_t)idx * 8;
    #pragma unroll
    for (int i = 0; i < 8; ++i) dst[i] = f2bf(src[i]);
}

__global__ void k_packh1(const float* __restrict__ Wl1, short* __restrict__ pack)
{
    int idx = blockIdx.x * 256 + threadIdx.x;       // 65536
    int lane = idx & 63;
    int ks = (idx >> 6) & 31;
    int w  = (idx >> 11) & 3;
    int nb = idx >> 13;                              // <8
    int np = nb * 64 + w * 16 + (lane & 15);         // <512 no permute
    int k  = ks * 32 + ((lane >> 4) << 3);
    const float* src = Wl1 + (size_t)np * 1024 + k;
    short* dst = pack + (size_t)idx * 8;
    #pragma unroll
    for (int i = 0; i < 8; ++i) dst[i] = f2bf(src[i]);
}

__global__ void k_packh2(const float* __restrict__ Wl2, short* __restrict__ pack)
{
    int idx = blockIdx.x * 256 + threadIdx.x;       // 12288
    int lane = idx & 63;
    int ks = (idx >> 6) & 15;
    int w  = (idx >> 10) & 3;
    int nb = idx >> 12;                              // <3
    int np = nb * 64 + w * 16 + (lane & 15);         // <192
    int k  = ks * 32 + ((lane >> 4) << 3);
    short* dst = pack + (size_t)idx * 8;
    if (np < ACTN) {
        const float* src = Wl2 + (size_t)np * 512 + k;
        #pragma unroll
        for (int i = 0; i < 8; ++i) dst[i] = f2bf(src[i]);
    } else {
        #pragma unroll
        for (int i = 0; i < 8; ++i) dst[i] = 0;
    }
}

// ---------------------------------------------------------------------------
// Permuted biases. b1p additionally includes Wih1 @ bc.
// ---------------------------------------------------------------------------
__global__ void k_bias(const float* __restrict__ Wih1, const float* __restrict__ bc,
                       const float* bih1, const float* bhh1,
                       const float* bih2, const float* bhh2,
                       const float* bih3, const float* bhh3,
                       float* b1p, float* b2p, float* b3p)
{
    int cp = blockIdx.x * 256 + threadIdx.x;        // 2048
    int n = (cp & 3) * 512 + (cp >> 2);
    float s = bih1[n] + bhh1[n];
    for (int m = 0; m < 512; ++m) s += Wih1[(size_t)n * 512 + m] * bc[m];
    b1p[cp] = s;
    b2p[cp] = bih2[n] + bhh2[n];
    b3p[cp] = bih3[n] + bhh3[n];
}

// ---------------------------------------------------------------------------
// Transpose (fp32), for WaHT
// ---------------------------------------------------------------------------
__global__ void k_tr(float* __restrict__ dst, const float* __restrict__ src,
                     int R, int C, int sld, int dld)
{
    int idx = blockIdx.x * 256 + threadIdx.x;
    if (idx >= R * C) return;
    int c = idx / R, r = idx - c * R;
    dst[c * dld + r] = src[r * sld + c];
}

// ---------------------------------------------------------------------------
// ENCP[b][l][h] = enc[b][l][:] . Wa1[h][:512] + ba1[h]
// ---------------------------------------------------------------------------
__launch_bounds__(256)
__global__ void k_encp(const float* __restrict__ enc, const float* __restrict__ Wa1,
                       const float* __restrict__ ba1, float* __restrict__ ENCP)
{
    __shared__ float wa[HATT * 513];
    __shared__ float er[8][513];
    int b = blockIdx.x, tid = threadIdx.x;
    for (int idx = tid; idx < HATT * 512; idx += 256) {
        int h = idx >> 9, e = idx & 511;
        wa[h * 513 + e] = Wa1[h * 1024 + e];
    }
    __syncthreads();
    for (int c = 0; c < 8; ++c) {
        for (int i = 0; i < 16; ++i) {
            int idx = tid + 256 * i;
            int rr = idx >> 9, e = idx & 511;
            er[rr][e] = enc[((size_t)b * LLEN + c * 8 + rr) * 512 + e];
        }
        __syncthreads();
        if (tid < 8 * HATT) {
            int rr = tid & 7, h = tid >> 3;
            float s = 0.f;
            for (int e = 0; e < 512; ++e) s += er[rr][e] * wa[h * 513 + e];
            ENCP[((size_t)b * LLEN + c * 8 + rr) * HATT + h] = s + ba1[h];
        }
        __syncthreads();
    }
}

// ---------------------------------------------------------------------------
// ET[t][b][k] = bf16(embW[act[b][t-1]][k]), zeros at t=0
// ---------------------------------------------------------------------------
__global__ void k_embed(const int* __restrict__ act, const float* __restrict__ embW,
                        short* __restrict__ ET)
{
    int idx = blockIdx.x * 256 + threadIdx.x;       // 128*256*128
    int t = idx >> 15;
    int rem = idx & 32767;
    int b = rem >> 7, k = rem & 127;
    float v = 0.f;
    if (t > 0) v = embW[(size_t)act[b * TLEN + t - 1] * EMBD + k];
    ET[idx] = f2bf(v);
}

// ---------------------------------------------------------------------------
// init: h (bf16) = enc_h, c (fp32) = enc_c, ctx = 0
// ---------------------------------------------------------------------------
__global__ void k_init(const float* __restrict__ eh, const float* __restrict__ ec,
                       short* h0, short* h1, short* h2,
                       float* c0, float* c1, float* c2, short* ctx)
{
    int i = blockIdx.x * 256 + threadIdx.x;         // 131072
    short hb = f2bf(eh[i]);
    float c = ec[i];
    h0[i] = hb; h1[i] = hb; h2[i] = hb;
    c0[i] = c;  c1[i] = c;  c2[i] = c;
    ctx[i] = 0;
}

// ---------------------------------------------------------------------------
// MFMA GEMM: C[256][N'] = A[256][K] @ W[K][N'], bf16 inputs, fp32 accum.
// Block: 32 rows x 64 cols, 4 waves (wave tile 32x16, 2 m-frags of 16x16x32).
// A staged in double-buffered XOR-swizzled LDS; B streamed prepacked from global.
// Sources: chunk kc<c1 -> s0 (or embedding gather if s0==nullptr), kc<c2 -> s1,
// else s2. 128-k chunks.
// EPI 0: LSTM cell update (gate-interleaved cols, c in-place, h out bf16)
// EPI 1: relu -> bf16 (head1)
// EPI 2: +bias -> fp32 out[(b*T+t)*129+col], col<129 (head2)
// ---------------------------------------------------------------------------
template<int EPI>
__launch_bounds__(256)
__global__ void k_mfma(const short* __restrict__ packB, const float* __restrict__ bias,
                       const short* __restrict__ s0, int ld0,
                       const short* __restrict__ s1, int ld1,
                       const short* __restrict__ s2, int ld2,
                       int c1, int c2, int kchunks,
                       const int* __restrict__ act, const float* __restrict__ embW, int t,
                       float* __restrict__ cbuf, short* __restrict__ hout,
                       float* __restrict__ fout)
{
    __shared__ short Asmem[2][32 * 128];
    int tid = threadIdx.x;
    int wave = tid >> 6, lane = tid & 63;
    int m0 = blockIdx.x * 32;
    int nb = blockIdx.y;
    int ksteps = kchunks * 4;
    const short* bptr = packB + ((size_t)(nb * 4 + wave) * ksteps) * 512 + lane * 8;

    auto stage = [&](int kc, int buf) {
        #pragma unroll
        for (int rep = 0; rep < 2; ++rep) {
            int ci = tid + rep * 256;
            int row = ci >> 4, k16 = ci & 15;
            bf16x8 v;
            if (kc < c1 && s0 == nullptr) {
                // embedding gather (LSTM1 chunk 0)
                int b = m0 + row;
                if (t == 0) {
                    v = (bf16x8)0;
                } else {
                    int a = act[b * TLEN + t - 1];
                    const float* e = embW + (size_t)a * EMBD + k16 * 8;
                    #pragma unroll
                    for (int i = 0; i < 8; ++i) v[i] = f2bf(e[i]);
                }
            } else {
                const short* s; int ld, kl;
                if (kc < c1)      { s = s0; ld = ld0; kl = kc; }
                else if (kc < c2) { s = s1; ld = ld1; kl = kc - c1; }
                else              { s = s2; ld = ld2; kl = kc - c2; }
                v = *(const bf16x8*)(s + (size_t)(m0 + row) * ld + kl * 128 + k16 * 8);
            }
            int byteoff = row * 256 + ((k16 * 16) ^ ((row & 7) << 4));
            *(bf16x8*)((char*)&Asmem[buf][0] + byteoff) = v;
        }
    };

    f32x4 acc[2] = {};
    stage(0, 0);
    __syncthreads();
    for (int kc = 0; kc < kchunks; ++kc) {
        int buf = kc & 1;
        if (kc + 1 < kchunks) stage(kc + 1, buf ^ 1);
        const char* base = (const char*)&Asmem[buf][0];
        #pragma unroll
        for (int ks = 0; ks < 4; ++ks) {
            bf16x8 bfrag = *(const bf16x8*)bptr;
            bptr += 512;
            #pragma unroll
            for (int mf = 0; mf < 2; ++mf) {
                int row = mf * 16 + (lane & 15);
                int colb = (ks * 32 + ((lane >> 4) << 3)) * 2;
                bf16x8 afrag = *(const bf16x8*)(base + row * 256 + (colb ^ ((row & 7) << 4)));
                acc[mf] = __builtin_amdgcn_mfma_f32_16x16x32_bf16(afrag, bfrag, acc[mf], 0, 0, 0);
            }
        }
        __syncthreads();
    }

    int colg = nb * 64 + wave * 16 + (lane & 15);
    int rbase = (lane >> 4) * 4;

    if constexpr (EPI == 0) {
        __shared__ float G[32][68];
        float bv = bias[colg];
        int lcol = wave * 16 + (lane & 15);
        #pragma unroll
        for (int mf = 0; mf < 2; ++mf)
            #pragma unroll
            for (int r = 0; r < 4; ++r)
                G[mf * 16 + rbase + r][lcol] = acc[mf][r] + bv;
        __syncthreads();
        #pragma unroll
        for (int it = 0; it < 2; ++it) {
            int item = tid + it * 256;
            int r = item >> 4, jl = item & 15;
            float gi = G[r][4 * jl + 0];
            float gf = G[r][4 * jl + 1];
            float gg = G[r][4 * jl + 2];
            float go = G[r][4 * jl + 3];
            int b = m0 + r;
            int j = nb * 16 + jl;
            float co = cbuf[b * 512 + j];
            float si = 1.f / (1.f + __expf(-gi));
            float sf = 1.f / (1.f + __expf(-gf));
            float so = 1.f / (1.f + __expf(-go));
            float cn = sf * co + si * tanhf(gg);
            float hn = so * tanhf(cn);
            cbuf[b * 512 + j] = cn;
            hout[b * 512 + j] = f2bf(hn);
        }
    } else if constexpr (EPI == 1) {
        float bv = bias[colg];
        #pragma unroll
        for (int mf = 0; mf < 2; ++mf)
            #pragma unroll
            for (int r = 0; r < 4; ++r) {
                int b = m0 + mf * 16 + rbase + r;
                hout[b * 512 + colg] = f2bf(fmaxf(acc[mf][r] + bv, 0.f));
            }
    } else {
        if (colg < ACTN) {
            float bv = bias[colg];
            #pragma unroll
            for (int mf = 0; mf < 2; ++mf)
                #pragma unroll
                for (int r = 0; r < 4; ++r) {
                    int b = m0 + mf * 16 + rbase + r;
                    fout[((size_t)b * TLEN + t) * ACTN + colg] = acc[mf][r] + bv;
                }
        }
    }
}

// ---------------------------------------------------------------------------
// Attention (bf16 h2 / ctx)
// ---------------------------------------------------------------------------
__launch_bounds__(256)
__global__ void k_attn(const short* __restrict__ h2, const float* __restrict__ enc,
                       const float* __restrict__ ENCP, const float* __restrict__ WaHT,
                       const float* __restrict__ Wa2, const float* __restrict__ ba2,
                       short* __restrict__ ctx)
{
    int b = blockIdx.x, tid = threadIdx.x;
    __shared__ float h2s[512];
    __shared__ float part[8][HATT];
    __shared__ float hp[HATT];
    __shared__ float sl[LLEN];
    h2s[tid]       = bf2f(h2[b * 512 + tid]);
    h2s[256 + tid] = bf2f(h2[b * 512 + 256 + tid]);
    __syncthreads();
    if (tid < 8 * HATT) {
        int h = tid % HATT, sg = tid / HATT;
        float s = 0.f;
        for (int e = sg * 64; e < sg * 64 + 64; ++e) s += h2s[e] * WaHT[e * HATT + h];
        part[sg][h] = s;
    }
    __syncthreads();
    if (tid < HATT) {
        float s = 0.f;
        for (int sg = 0; sg < 8; ++sg) s += part[sg][tid];
        hp[tid] = s;
    }
    __syncthreads();
    if (tid < LLEN) {
        float s = ba2[0];
        const float* ep = ENCP + ((size_t)b * LLEN + tid) * HATT;
        #pragma unroll
        for (int h = 0; h < HATT; ++h)
            s += fmaxf(ep[h] + hp[h], 0.f) * Wa2[h];
        float v = tanhf(s);
        float m = v;
        for (int off = 32; off; off >>= 1) m = fmaxf(m, __shfl_xor(m, off));
        float e = __expf(v - m);
        float ssum = e;
        for (int off = 32; off; off >>= 1) ssum += __shfl_xor(ssum, off);
        sl[tid] = e / ssum;
    }
    __syncthreads();
    for (int e = tid; e < 512; e += 256) {
        float acc = 0.f;
        for (int l = 0; l < LLEN; ++l)
            acc += sl[l] * enc[((size_t)b * LLEN + l) * 512 + e];
        ctx[b * 512 + e] = f2bf(acc);
    }
}

// ---------------------------------------------------------------------------
extern "C" void kernel_launch(void* const* d_in, const int* in_sizes, int n_in,
                              void* d_out, int out_size, void* d_ws, size_t ws_size,
                              hipStream_t stream)
{
    const int*   act   = (const int*)d_in[0];
    const float* enc   = (const float*)d_in[1];
    const float* enc_h = (const float*)d_in[2];
    const float* enc_c = (const float*)d_in[3];
    const float* embW  = (const float*)d_in[4];
    const float* Wc    = (const float*)d_in[5];
    const float* bc    = (const float*)d_in[6];
    const float* Wih1  = (const float*)d_in[7];
    const float* Whh1  = (const float*)d_in[8];
    const float* bih1  = (const float*)d_in[9];
    const float* bhh1  = (const float*)d_in[10];
    const float* Wih2  = (const float*)d_in[11];
    const float* Whh2  = (const float*)d_in[12];
    const float* bih2  = (const float*)d_in[13];
    const float* bhh2  = (const float*)d_in[14];
    const float* Wih3  = (const float*)d_in[15];
    const float* Whh3  = (const float*)d_in[16];
    const float* bih3  = (const float*)d_in[17];
    const float* bhh3  = (const float*)d_in[18];
    const float* Wa1   = (const float*)d_in[19];
    const float* ba1   = (const float*)d_in[20];
    const float* Wa2   = (const float*)d_in[21];
    const float* ba2   = (const float*)d_in[22];
    const float* Wl1   = (const float*)d_in[23];
    const float* bl1   = (const float*)d_in[24];
    const float* Wl2   = (const float*)d_in[25];
    const float* bl2   = (const float*)d_in[26];
    float* out = (float*)d_out;

    char* cur = (char*)d_ws;
    auto alloc = [&](size_t bytes) {
        char* p = cur;
        cur += (bytes + 255) & ~(size_t)255;
        return p;
    };
    short* pack1  = (short*)alloc((size_t)2048 * 1152 * 2);
    short* pack2  = (short*)alloc((size_t)2048 * 1024 * 2);
    short* pack3  = (short*)alloc((size_t)2048 * 1024 * 2);
    short* packh1 = (short*)alloc((size_t)512 * 1024 * 2);
    short* packh2 = (short*)alloc((size_t)192 * 512 * 2);
    float* W1f    = (float*)alloc((size_t)2048 * 640 * 4);
    float* b1p    = (float*)alloc(2048 * 4);
    float* b2p    = (float*)alloc(2048 * 4);
    float* b3p    = (float*)alloc(2048 * 4);
    float* WaHT   = (float*)alloc(512 * HATT * 4);
    float* ENCP   = (float*)alloc((size_t)BSZ * LLEN * HATT * 4);
    short* ET     = (short*)alloc((size_t)TLEN * BSZ * EMBD * 2);
    const size_t SB = (size_t)BSZ * DH;
    short* h0[2] = { (short*)alloc(SB * 2), (short*)alloc(SB * 2) };
    short* h1[2] = { (short*)alloc(SB * 2), (short*)alloc(SB * 2) };
    short* h2[2] = { (short*)alloc(SB * 2), (short*)alloc(SB * 2) };
    float* c0 = (float*)alloc(SB * 4);
    float* c1b = (float*)alloc(SB * 4);
    float* c2b = (float*)alloc(SB * 4);
    short* ctx    = (short*)alloc(SB * 2);
    short* hidden = (short*)alloc(SB * 2);

    // ---- prep ----
    k_fold<<<dim3(32, 10), 256, 0, stream>>>(Wih1, Wc, W1f);
    k_pack1<<<1152, 256, 0, stream>>>(W1f, Whh1, pack1);
    k_pack23<<<1024, 256, 0, stream>>>(Wih2, Whh2, pack2);
    k_pack23<<<1024, 256, 0, stream>>>(Wih3, Whh3, pack3);
    k_packh1<<<256, 256, 0, stream>>>(Wl1, packh1);
    k_packh2<<<48, 256, 0, stream>>>(Wl2, packh2);
    k_bias<<<8, 256, 0, stream>>>(Wih1, bc, bih1, bhh1, bih2, bhh2, bih3, bhh3,
                                  b1p, b2p, b3p);
    k_tr<<<(HATT * 512 + 255) / 256, 256, 0, stream>>>(WaHT, Wa1 + 512, HATT, 512, 1024, HATT);
    k_encp<<<BSZ, 256, 0, stream>>>(enc, Wa1, ba1, ENCP);
    k_embed<<<(TLEN * BSZ * EMBD) / 256, 256, 0, stream>>>(act, embW, ET);
    k_init<<<512, 256, 0, stream>>>(enc_h, enc_c, h0[0], h1[0], h2[0], c0, c1b, c2b, ctx);

    // ---- recurrent loop ----
    for (int t = 0; t < TLEN; ++t) {
        int p = t & 1, q = p ^ 1;
        // LSTM1: A = [emb(t-1) | ctx | h0], K=1152 (9 chunks)
        k_mfma<0><<<dim3(8, 32), 256, 0, stream>>>(
            pack1, b1p,
            nullptr, 128, ctx, 512, h0[p], 512,
            1, 5, 9, act, embW, t,
            c0, h0[q], nullptr);
        // LSTM2: A = [h0_new | h1_old]
        k_mfma<0><<<dim3(8, 32), 256, 0, stream>>>(
            pack2, b2p,
            h0[q], 512, h1[p], 512, h1[p], 512,
            4, 8, 8, act, embW, t,
            c1b, h1[q], nullptr);
        // LSTM3
        k_mfma<0><<<dim3(8, 32), 256, 0, stream>>>(
            pack3, b3p,
            h1[q], 512, h2[p], 512, h2[p], 512,
            4, 8, 8, act, embW, t,
            c2b, h2[q], nullptr);
        // attention -> ctx
        k_attn<<<BSZ, 256, 0, stream>>>(h2[q], enc, ENCP, WaHT, Wa2, ba2, ctx);
        // head1: A = [h2 | ctx]
        k_mfma<1><<<dim3(8, 8), 256, 0, stream>>>(
            packh1, bl1,
            h2[q], 512, ctx, 512, ctx, 512,
            4, 8, 8, act, embW, t,
            nullptr, hidden, nullptr);
        // head2: A = hidden, N'=192 (129 live)
        k_mfma<2><<<dim3(8, 3), 256, 0, stream>>>(
            packh2, bl2,
            hidden, 512, hidden, 512, hidden, 512,
            4, 4, 4, act, embW, t,
            nullptr, nullptr, out);
    }
}